// Round 5
// baseline (11.598 us; speedup 1.0000x reference)
//
#include <hip/hip_runtime.h>

#define NS 512

// ============================================================================
// Fully-fused single kernel, closed-form circuits (verified R3/R4).
//   Per (token,head): A=c1c2c3, B=c0c1, C=B*c2, W=vc3*C*c3 + vs3*s0s1s3c2
//   Q=aQ*A, K=aK*A, V=(vc0*A, vc1*B, vc2*C, W)  -- vc* applied AFTER reduce.
//   attention = row-softmax of exp(-0.5 (Qi-Kj)^2)  (logits in [-2,0])
// Block = (batch b, rowgroup rg of 16 rows), 256 threads.
//   P1: pack {A,B,C,W} both heads, all 512 tokens -> LDS (one b128/j in P2)
//   P2: 16 tasks (8 row-pairs x 2 heads) x 16 lanes; 2 rows share each K/V read
//   P3: 16 threads: 8-wire merge closed form + residual -> out
// ============================================================================

__global__ __launch_bounds__(256)
void k_fused(const float* __restrict__ x, const float* __restrict__ Vw,
             const float* __restrict__ Qw, const float* __restrict__ Kw,
             const float* __restrict__ Mw, float* __restrict__ out)
{
    __shared__ float4 As4[2][NS];     // {A,B,C,W} per head per token
    __shared__ float  HOs[16][8];

    int tid = threadIdx.x;
    int b   = blockIdx.x >> 5;
    int rg  = blockIdx.x & 31;

    // ---- per-head weight constants as NAMED scalars (no runtime-indexed arrays) ----
    float sT, cT, sB, cB, s3;
    __sincosf(Qw[1],  &sT, &cT); __sincosf(Qw[12], &sB, &cB);
    float aQ0 = cB*cT + sB*sT*__sinf(Qw[2]);
    __sincosf(Qw[14], &sT, &cT); __sincosf(Qw[25], &sB, &cB);
    float aQ1 = cB*cT + sB*sT*__sinf(Qw[15]);
    __sincosf(Kw[1],  &sT, &cT); __sincosf(Kw[12], &sB, &cB);
    float aK0 = cB*cT + sB*sT*__sinf(Kw[2]);
    __sincosf(Kw[14], &sT, &cT); __sincosf(Kw[25], &sB, &cB);
    float aK1 = cB*cT + sB*sT*__sinf(Kw[15]);
    float vc0_0 = __cosf(Vw[1]),  vc1_0 = __cosf(Vw[4]),  vc2_0 = __cosf(Vw[7]);
    float vc3_0; __sincosf(Vw[10], &s3, &vc3_0);
    float vs3_0 = s3 * __sinf(Vw[9]);
    float vc0_1 = __cosf(Vw[13]), vc1_1 = __cosf(Vw[16]), vc2_1 = __cosf(Vw[19]);
    float vc3_1; __sincosf(Vw[22], &s3, &vc3_1);
    float vs3_1 = s3 * __sinf(Vw[21]);

    // ---- phase 1: pack {A,B,C,W} for 2 tokens/thread, both heads ----
    #pragma unroll
    for (int k = 0; k < 2; ++k) {
        int tl = tid + k*256;
        const float4* xp = (const float4*)(x + (b*NS + tl)*8);
        float4 xa = xp[0], xb = xp[1];
        float xv[8] = {xa.x, xa.y, xa.z, xa.w, xb.x, xb.y, xb.z, xb.w};
        float m = 0.f;
        #pragma unroll
        for (int e = 0; e < 8; ++e) m += xv[e];
        m *= 0.125f;
        float var = 0.f;
        #pragma unroll
        for (int e = 0; e < 8; ++e) { float d = xv[e]-m; var += d*d; }
        float inv = rsqrtf(var*0.125f + 1e-5f);

        float cg[8], sg[8];
        #pragma unroll
        for (int i = 0; i < 8; ++i)
            __sincosf((xv[i]-m)*inv, &sg[i], &cg[i]);

        {   // head 0: elements 0..3
            float A = cg[1]*cg[2]*cg[3];
            float B = cg[0]*cg[1];
            float C = B*cg[2];
            float W = vc3_0*(C*cg[3]) + vs3_0*(sg[0]*sg[1]*sg[3]*cg[2]);
            As4[0][tl] = make_float4(A, B, C, W);
        }
        {   // head 1: elements 4..7
            float A = cg[5]*cg[6]*cg[7];
            float B = cg[4]*cg[5];
            float C = B*cg[6];
            float W = vc3_1*(C*cg[7]) + vs3_1*(sg[4]*sg[5]*sg[7]*cg[6]);
            As4[1][tl] = make_float4(A, B, C, W);
        }
    }
    __syncthreads();

    // ---- phase 2: attention; 16 lanes per (row-pair, head) task ----
    {
        int lane = tid & 63;
        int w    = tid >> 6;
        int t16  = w*4 + (lane >> 4);   // task 0..15
        int l16  = lane & 15;
        int hh   = t16 >> 3;            // head (wave-uniform)
        int rp   = t16 & 7;             // row pair
        int ra   = rg*16 + rp*2;        // rows ra, ra+1

        float aK = hh ? aK1 : aK0;
        float aQ = hh ? aQ1 : aQ0;
        const float* Af = (const float*)As4;
        float qa = aQ * Af[(hh*NS + ra)*4];
        float qb = aQ * Af[(hh*NS + ra + 1)*4];

        float s0=0.f, A0=0.f, B0=0.f, C0=0.f, W0=0.f;
        float s1=0.f, A1=0.f, B1=0.f, C1=0.f, W1=0.f;
        #pragma unroll 8
        for (int k = 0; k < 32; ++k) {
            int j = k*16 + l16;
            float4 P = As4[hh][j];
            float kv = aK * P.x;
            float da = qa - kv, db = qb - kv;
            float pa = __expf(-0.5f*da*da);
            float pb = __expf(-0.5f*db*db);
            s0 += pa; A0 += pa*P.x; B0 += pa*P.y; C0 += pa*P.z; W0 += pa*P.w;
            s1 += pb; A1 += pb*P.x; B1 += pb*P.y; C1 += pb*P.z; W1 += pb*P.w;
        }
        #pragma unroll
        for (int off = 1; off < 16; off <<= 1) {
            s0 += __shfl_xor(s0, off, 16); A0 += __shfl_xor(A0, off, 16);
            B0 += __shfl_xor(B0, off, 16); C0 += __shfl_xor(C0, off, 16);
            W0 += __shfl_xor(W0, off, 16);
            s1 += __shfl_xor(s1, off, 16); A1 += __shfl_xor(A1, off, 16);
            B1 += __shfl_xor(B1, off, 16); C1 += __shfl_xor(C1, off, 16);
            W1 += __shfl_xor(W1, off, 16);
        }
        if (l16 < 2) {
            float ss = l16 ? s1 : s0;
            float sA = l16 ? A1 : A0;
            float sBv= l16 ? B1 : B0;
            float sC = l16 ? C1 : C0;
            float sW = l16 ? W1 : W0;
            float r  = 1.0f / ss;
            float v0 = hh ? vc0_1 : vc0_0;
            float v1 = hh ? vc1_1 : vc1_0;
            float v2 = hh ? vc2_1 : vc2_0;
            int rr = rp*2 + l16;
            HOs[rr][hh*4 + 0] = v0*sA*r;
            HOs[rr][hh*4 + 1] = v1*sBv*r;
            HOs[rr][hh*4 + 2] = v2*sC*r;
            HOs[rr][hh*4 + 3] = sW*r;
        }
    }
    __syncthreads();

    // ---- phase 3: merge closed form + residual, 16 threads ----
    if (tid < 16) {
        float cT0 = __cosf(Mw[1]);
        float cT1 = __cosf(Mw[4]);
        float cT2 = __cosf(Mw[7]);
        float cT3 = __cosf(Mw[10]);
        float cT4 = __cosf(Mw[13]);
        float cT5 = __cosf(Mw[16]);
        float cT6 = __cosf(Mw[19]);
        float s7w, cT7; __sincosf(Mw[22], &s7w, &cT7);
        float vs77 = s7w * __sinf(Mw[21]);

        int t = b*NS + rg*16 + tid;
        float a[8];
        #pragma unroll
        for (int e = 0; e < 8; ++e) a[e] = HOs[tid][e];

        float ca[8], sa0, sa1, sa7;
        __sincosf(a[0], &sa0, &ca[0]);
        __sincosf(a[1], &sa1, &ca[1]);
        ca[2] = __cosf(a[2]);
        ca[3] = __cosf(a[3]);
        ca[4] = __cosf(a[4]);
        ca[5] = __cosf(a[5]);
        ca[6] = __cosf(a[6]);
        __sincosf(a[7], &sa7, &ca[7]);

        float P1 = ca[0]*ca[1];
        float P2 = P1*ca[2];
        float P3 = P2*ca[3];
        float P4 = P3*ca[4];
        float P5 = P4*ca[5];
        float P6 = P5*ca[6];
        float P7 = P6*ca[7];
        float c34 = ca[3]*ca[4], c56 = ca[5]*ca[6];
        float Q17 = ca[1]*ca[2]*c34*c56*ca[7];
        float M26 = ca[2]*c34*c56;

        const float4* xp = (const float4*)(x + t*8);
        float4 x0 = xp[0], x1 = xp[1];
        float4 o0 = {cT0*Q17 + x0.x, cT1*P1 + x0.y, cT2*P2 + x0.z, cT3*P3 + x0.w};
        float4 o1 = {cT4*P4 + x1.x, cT5*P5 + x1.y, cT6*P6 + x1.z,
                     cT7*P7 + vs77*sa0*sa1*sa7*M26 + x1.w};
        float4* op = (float4*)(out + t*8);
        op[0] = o0; op[1] = o1;
    }
}

// ======================= launch =======================
extern "C" void kernel_launch(void* const* d_in, const int* in_sizes, int n_in,
                              void* d_out, int out_size, void* d_ws, size_t ws_size,
                              hipStream_t stream) {
    (void)in_sizes; (void)n_in; (void)out_size; (void)d_ws; (void)ws_size;
    const float* x  = (const float*)d_in[0];
    const float* Vw = (const float*)d_in[1];
    const float* Qw = (const float*)d_in[2];
    const float* Kw = (const float*)d_in[3];
    const float* Mw = (const float*)d_in[4];
    float* out = (float*)d_out;

    hipLaunchKernelGGL(k_fused, dim3(512), dim3(256), 0, stream,
                       x, Vw, Qw, Kw, Mw, out);
}

// Round 7
// 10.719 us; speedup vs baseline: 1.0819x; 1.0819x over previous
//
#include <hip/hip_runtime.h>

#define NS 512
// sqrt(0.5*log2(e)) : exp(-0.5 d^2) == exp2(-(SC*d)^2)
#define SC 0.8493218002880191f

// ============================================================================
// Fully-fused single kernel, closed-form circuits (verified R3..R5).
//   Per (token,head): A=c1c2c3, B=c0c1, C=B*c2, W=vc3*C*c3 + vs3*s0s1s3c2
//   Qt=SC*aQ*A, Kt=SC*aK*A ; p = exp2(-(Qt_i-Kt_j)^2)  (exact fold)
//   V=(vc0*A, vc1*B, vc2*C, W) -- vc* applied AFTER the p-weighted reduce.
// Block = (batch b, rowgroup rg of 32 rows), 512 threads = 8 waves.
//   P1: pack {A,B,C,W} both heads, all 512 tokens -> LDS (1 token/thread)
//   P2: per wave: 4 tasks = 2 row-pairs x 2 heads, 16 lanes/task, 32 j/lane
//       butterfly-reduce in 16 lanes; heads exchanged via shfl_xor(32)
//   P3: lanes {0,1,16,17} of each wave: 8-wire merge closed form + residual
// ============================================================================

__global__ __launch_bounds__(512)
void k_fused(const float* __restrict__ x, const float* __restrict__ Vw,
             const float* __restrict__ Qw, const float* __restrict__ Kw,
             const float* __restrict__ Mw, float* __restrict__ out)
{
    __shared__ float4 As4[2][NS];     // {A,B,C,W} per head per token

    int tid = threadIdx.x;
    int b   = blockIdx.x >> 4;
    int rg  = blockIdx.x & 15;

    // ---- uniform weight-derived constants (named scalars) ----
    float sT, cT, sB, cB, s3;
    __sincosf(Qw[1],  &sT, &cT); __sincosf(Qw[12], &sB, &cB);
    float aQ0 = (cB*cT + sB*sT*__sinf(Qw[2]))  * SC;
    __sincosf(Qw[14], &sT, &cT); __sincosf(Qw[25], &sB, &cB);
    float aQ1 = (cB*cT + sB*sT*__sinf(Qw[15])) * SC;
    __sincosf(Kw[1],  &sT, &cT); __sincosf(Kw[12], &sB, &cB);
    float aK0 = (cB*cT + sB*sT*__sinf(Kw[2]))  * SC;
    __sincosf(Kw[14], &sT, &cT); __sincosf(Kw[25], &sB, &cB);
    float aK1 = (cB*cT + sB*sT*__sinf(Kw[15])) * SC;
    float vc0_0 = __cosf(Vw[1]),  vc1_0 = __cosf(Vw[4]),  vc2_0 = __cosf(Vw[7]);
    float vc3_0; __sincosf(Vw[10], &s3, &vc3_0);
    float vs3_0 = s3 * __sinf(Vw[9]);
    float vc0_1 = __cosf(Vw[13]), vc1_1 = __cosf(Vw[16]), vc2_1 = __cosf(Vw[19]);
    float vc3_1; __sincosf(Vw[22], &s3, &vc3_1);
    float vs3_1 = s3 * __sinf(Vw[21]);
    // merge-layer constants
    float cT0 = __cosf(Mw[1]);
    float cT1 = __cosf(Mw[4]);
    float cT2 = __cosf(Mw[7]);
    float cT3 = __cosf(Mw[10]);
    float cT4 = __cosf(Mw[13]);
    float cT5 = __cosf(Mw[16]);
    float cT6 = __cosf(Mw[19]);
    float s7w, cT7; __sincosf(Mw[22], &s7w, &cT7);
    float vs77 = s7w * __sinf(Mw[21]);

    // ---- phase 1: pack {A,B,C,W}, one token per thread ----
    {
        int tl = tid;
        const float4* xp = (const float4*)(x + (b*NS + tl)*8);
        float4 xa = xp[0], xb = xp[1];
        float xv[8] = {xa.x, xa.y, xa.z, xa.w, xb.x, xb.y, xb.z, xb.w};
        float m = 0.f;
        #pragma unroll
        for (int e = 0; e < 8; ++e) m += xv[e];
        m *= 0.125f;
        float var = 0.f;
        #pragma unroll
        for (int e = 0; e < 8; ++e) { float d = xv[e]-m; var += d*d; }
        float inv = rsqrtf(var*0.125f + 1e-5f);

        float cg[8], sg[8];
        #pragma unroll
        for (int i = 0; i < 8; ++i)
            __sincosf((xv[i]-m)*inv, &sg[i], &cg[i]);

        {   // head 0
            float A = cg[1]*cg[2]*cg[3];
            float B = cg[0]*cg[1];
            float C = B*cg[2];
            float W = vc3_0*(C*cg[3]) + vs3_0*(sg[0]*sg[1]*sg[3]*cg[2]);
            As4[0][tl] = make_float4(A, B, C, W);
        }
        {   // head 1
            float A = cg[5]*cg[6]*cg[7];
            float B = cg[4]*cg[5];
            float C = B*cg[6];
            float W = vc3_1*(C*cg[7]) + vs3_1*(sg[4]*sg[5]*sg[7]*cg[6]);
            As4[1][tl] = make_float4(A, B, C, W);
        }
    }
    __syncthreads();

    // ---- phase 2: attention ----
    int lane = tid & 63;
    int w    = tid >> 6;            // wave 0..7
    int hh   = lane >> 5;           // head (half-wave uniform)
    int rpw  = (lane >> 4) & 1;     // row-pair within wave
    int l16  = lane & 15;
    int ra   = rg*32 + (w*2 + rpw)*2;   // rows ra, ra+1

    float aK = hh ? aK1 : aK0;
    float aQ = hh ? aQ1 : aQ0;
    const float* Af = (const float*)As4;
    float qa = aQ * Af[(hh*NS + ra)*4];
    float qb = aQ * Af[(hh*NS + ra + 1)*4];

    float s0=0.f, A0=0.f, B0=0.f, C0=0.f, W0=0.f;
    float s1=0.f, A1=0.f, B1=0.f, C1=0.f, W1=0.f;
    #pragma unroll 8
    for (int k = 0; k < 32; ++k) {
        int j = k*16 + l16;
        float4 P = As4[hh][j];
        float kv = aK * P.x;
        float da = qa - kv, db = qb - kv;
        float pa = __builtin_amdgcn_exp2f(-(da*da));
        float pb = __builtin_amdgcn_exp2f(-(db*db));
        s0 += pa; A0 += pa*P.x; B0 += pa*P.y; C0 += pa*P.z; W0 += pa*P.w;
        s1 += pb; A1 += pb*P.x; B1 += pb*P.y; C1 += pb*P.z; W1 += pb*P.w;
    }
    #pragma unroll
    for (int off = 1; off < 16; off <<= 1) {
        s0 += __shfl_xor(s0, off, 16); A0 += __shfl_xor(A0, off, 16);
        B0 += __shfl_xor(B0, off, 16); C0 += __shfl_xor(C0, off, 16);
        W0 += __shfl_xor(W0, off, 16);
        s1 += __shfl_xor(s1, off, 16); A1 += __shfl_xor(A1, off, 16);
        B1 += __shfl_xor(B1, off, 16); C1 += __shfl_xor(C1, off, 16);
        W1 += __shfl_xor(W1, off, 16);
    }

    // normalized half-row HO for row (ra + (l16&1)), this head — all lanes
    float ss  = (l16 & 1) ? s1 : s0;
    float sA  = (l16 & 1) ? A1 : A0;
    float sBv = (l16 & 1) ? B1 : B0;
    float sCv = (l16 & 1) ? C1 : C0;
    float sW  = (l16 & 1) ? W1 : W0;
    float rr = 1.0f / ss;
    float v0 = hh ? vc0_1 : vc0_0;
    float v1 = hh ? vc1_1 : vc1_0;
    float v2 = hh ? vc2_1 : vc2_0;
    float ho0 = v0*sA*rr;
    float ho1 = v1*sBv*rr;
    float ho2 = v2*sCv*rr;
    float ho3 = sW*rr;

    // exchange heads across the half-wave boundary (must be exec-uniform)
    float ho4 = __shfl_xor(ho0, 32, 64);
    float ho5 = __shfl_xor(ho1, 32, 64);
    float ho6 = __shfl_xor(ho2, 32, 64);
    float ho7 = __shfl_xor(ho3, 32, 64);

    // ---- phase 3: merge + residual, lanes {0,1,16,17} (hh==0, l16<2) ----
    if (hh == 0 && l16 < 2) {
        int t = b*NS + ra + l16;
        float a0v=ho0, a1v=ho1, a2v=ho2, a3v=ho3;
        float a4v=ho4, a5v=ho5, a6v=ho6, a7v=ho7;

        float ca0, ca1, ca7, sa0, sa1, sa7;
        __sincosf(a0v, &sa0, &ca0);
        __sincosf(a1v, &sa1, &ca1);
        float ca2 = __cosf(a2v);
        float ca3 = __cosf(a3v);
        float ca4 = __cosf(a4v);
        float ca5 = __cosf(a5v);
        float ca6 = __cosf(a6v);
        __sincosf(a7v, &sa7, &ca7);

        float P1 = ca0*ca1;
        float P2 = P1*ca2;
        float P3 = P2*ca3;
        float P4 = P3*ca4;
        float P5 = P4*ca5;
        float P6 = P5*ca6;
        float P7 = P6*ca7;
        float c34 = ca3*ca4, c56 = ca5*ca6;
        float Q17 = ca1*ca2*c34*c56*ca7;
        float M26 = ca2*c34*c56;

        const float4* xp = (const float4*)(x + t*8);
        float4 x0 = xp[0], x1 = xp[1];
        float4 o0 = {cT0*Q17 + x0.x, cT1*P1 + x0.y, cT2*P2 + x0.z, cT3*P3 + x0.w};
        float4 o1 = {cT4*P4 + x1.x, cT5*P5 + x1.y, cT6*P6 + x1.z,
                     cT7*P7 + vs77*sa0*sa1*sa7*M26 + x1.w};
        float4* op = (float4*)(out + t*8);
        op[0] = o0; op[1] = o1;
    }
}

// ======================= launch =======================
extern "C" void kernel_launch(void* const* d_in, const int* in_sizes, int n_in,
                              void* d_out, int out_size, void* d_ws, size_t ws_size,
                              hipStream_t stream) {
    (void)in_sizes; (void)n_in; (void)out_size; (void)d_ws; (void)ws_size;
    const float* x  = (const float*)d_in[0];
    const float* Vw = (const float*)d_in[1];
    const float* Qw = (const float*)d_in[2];
    const float* Kw = (const float*)d_in[3];
    const float* Mw = (const float*)d_in[4];
    float* out = (float*)d_out;

    hipLaunchKernelGGL(k_fused, dim3(256), dim3(512), 0, stream,
                       x, Vw, Qw, Kw, Mw, out);
}